// Round 10
// baseline (231.388 us; speedup 1.0000x reference)
//
#include <hip/hip_runtime.h>
#include <math.h>

#define N_NODES 50000
#define E_EDGES 500000
#define P_PAIRS 200000
#define MAX_DEG 64    // Binomial(500k,1/50k): P(deg>=64) ~ 1e-28 per node
#define FIL_PAD 16    // one counter per 64-B line: kills atomic line contention

typedef __bf16    bf16x8 __attribute__((ext_vector_type(8)));
typedef _Float16  f16x8  __attribute__((ext_vector_type(8)));
typedef float     f32x4  __attribute__((ext_vector_type(4)));

// ---------------- fused prologue: conv_x  ||  slot-fill  ||  weight pack ----------------
// All three phases independent (fil pre-zeroed by memset before this kernel).
// P1/P2 (layer weights, K=256,N=128): [kt(8)][nt(8)][lane(64)][j(8)]
//   n = nt*16+(lane&15), k = kt*32+(lane>>4)*8+j ; k<128 -> Wl[n][k], else Wr[n][k-128]
// P4 (pair weights, K=128,N=256):     [kt(4)][nt(16)][lane(64)][j(8)]
//   n'= nt*16+(lane&15), k = kt*32+(lane>>4)*8+j ; n'<128 -> W3[n'][k], else W3[n'-128][128+k]

#define CONV_BLKS 6250   // N_NODES*128/4/256
#define FILL_BLKS 1954   // ceil(E/256)
#define PREP_BLKS 128    // 32768/256

__global__ __launch_bounds__(256) void fused_pre_k(
        const float* __restrict__ x, __bf16* __restrict__ xb,
        const int* __restrict__ src, const int* __restrict__ dst,
        int* __restrict__ fil, int* __restrict__ slots,
        const float* __restrict__ Wl1, const float* __restrict__ Wr1,
        const float* __restrict__ Wl2, const float* __restrict__ Wr2,
        const float* __restrict__ W3,
        __bf16* __restrict__ P1, __bf16* __restrict__ P2, __bf16* __restrict__ P4) {
    int b = blockIdx.x, t = threadIdx.x;
    if (b < CONV_BLKS) {
        int i = b * 256 + t;                      // float4 index
        float4 v = ((const float4*)x)[i];
        __bf16* o = xb + (size_t)i * 4;
        o[0] = (__bf16)v.x; o[1] = (__bf16)v.y; o[2] = (__bf16)v.z; o[3] = (__bf16)v.w;
    } else if (b < CONV_BLKS + FILL_BLKS) {
        int e = (b - CONV_BLKS) * 256 + t;
        if (e < E_EDGES) {
            int d = dst[e];
            int pos = atomicAdd(&fil[d * FIL_PAD], 1);   // padded: ~10 atomics/line
            if (pos < MAX_DEG)
                __builtin_nontemporal_store(src[e], &slots[d * MAX_DEG + pos]);
        }
    } else {
        int i = (b - CONV_BLKS - FILL_BLKS) * 256 + t;   // 0..32767
        int lane = (i >> 3) & 63;
        int j = i & 7;
        int kq = (lane >> 4) * 8 + j;
        // P1/P2: K=256 layout
        {
            int kt = i >> 12, nt = (i >> 9) & 7;
            int n = nt * 16 + (lane & 15);
            int k = kt * 32 + kq;
            P1[i] = (__bf16)((k < 128) ? Wl1[n * 128 + k] : Wr1[n * 128 + (k - 128)]);
            P2[i] = (__bf16)((k < 128) ? Wl2[n * 128 + k] : Wr2[n * 128 + (k - 128)]);
        }
        // P4: K=128, N=256 layout
        {
            int kt = i >> 13, nt = (i >> 9) & 15;
            int n = nt * 16 + (lane & 15);
            int k = kt * 32 + kq;
            P4[i] = (__bf16)((n < 128) ? W3[n * 256 + k] : W3[(n - 128) * 256 + 128 + k]);
        }
    }
}

// ---------------- segment-mean aggregation: one wave per node, slot table ----------------
// Aligned 256-B coalesced neighbor-ID load; wave-uniform trip count so every
// ds_bpermute runs with full exec (inactive-lane bpermute returns 0 -- R7 bug);
// accumulation predicated per-lane. Lanes >= deg sanitize their ID to 0.

__global__ __launch_bounds__(256) void agg1_k(const __bf16* __restrict__ feat,
                                              const int* __restrict__ fil,
                                              const int* __restrict__ slots,
                                              __bf16* __restrict__ agg) {
    int n = blockIdx.x * 4 + (threadIdx.x >> 6);
    if (n >= N_NODES) return;
    int lane = threadIdx.x & 63;
    int slot = lane >> 4, l = lane & 15;
    int deg = fil[n * FIL_PAD];
    int nit = (deg < MAX_DEG) ? deg : MAX_DEG;

    int ed = (lane < nit) ? slots[n * MAX_DEG + lane] : 0;  // coalesced, sanitized

    float s[8];
    #pragma unroll
    for (int e = 0; e < 8; ++e) s[e] = 0.f;

    int trips = (nit + 3) >> 2;       // wave-uniform
    int it = slot;
    int k = 0;
    for (; k + 1 < trips; k += 2, it += 8) {
        int sn0 = __builtin_amdgcn_ds_bpermute(it << 2, ed);        // full exec
        int sn1 = __builtin_amdgcn_ds_bpermute((it + 4) << 2, ed);  // full exec
        bf16x8 v0 = *(const bf16x8*)(feat + (size_t)sn0 * 128 + l * 8);
        bf16x8 v1 = *(const bf16x8*)(feat + (size_t)sn1 * 128 + l * 8);
        if (it < nit) {
            #pragma unroll
            for (int e = 0; e < 8; ++e) s[e] += (float)v0[e];
        }
        if (it + 4 < nit) {
            #pragma unroll
            for (int e = 0; e < 8; ++e) s[e] += (float)v1[e];
        }
    }
    if (k < trips) {
        int sn = __builtin_amdgcn_ds_bpermute(it << 2, ed);         // full exec
        bf16x8 v = *(const bf16x8*)(feat + (size_t)sn * 128 + l * 8);
        if (it < nit) {
            #pragma unroll
            for (int e = 0; e < 8; ++e) s[e] += (float)v[e];
        }
    }

    // reduce the 4 slots (full exec: all lanes of the wave reach this)
    #pragma unroll
    for (int e = 0; e < 8; ++e) {
        s[e] += __shfl_xor(s[e], 16, 64);
        s[e] += __shfl_xor(s[e], 32, 64);
    }

    if (slot == 0) {
        float inv = 1.0f / fmaxf((float)deg, 1.0f);
        bf16x8 o;
        #pragma unroll
        for (int e = 0; e < 8; ++e) o[e] = (__bf16)(s[e] * inv);
        *(bf16x8*)(agg + (size_t)n * 128 + l * 8) = o;
    }
}

// ---------------- layer 1: out = relu([agg|feat] @ B + bias), 16 rows/wave ----------------

__global__ __launch_bounds__(256) void layer_mfma_k(const __bf16* __restrict__ agg,
                                                    const __bf16* __restrict__ feat,
                                                    const __bf16* __restrict__ wpack,
                                                    const float* __restrict__ bias,
                                                    __bf16* __restrict__ out) {
    int wave = threadIdx.x >> 6;
    int lane = threadIdx.x & 63;
    int m = lane & 15, quad = lane >> 4;
    int rbase = blockIdx.x * 64 + wave * 16;
    int r0 = rbase + m; if (r0 > N_NODES - 1) r0 = N_NODES - 1;

    f32x4 acc[8];
    #pragma unroll
    for (int nt = 0; nt < 8; ++nt) acc[nt] = (f32x4)0.f;

    #pragma unroll
    for (int kt = 0; kt < 8; ++kt) {
        const __bf16* src = (kt < 4) ? agg : feat;
        int ko = (kt & 3) * 32 + quad * 8;
        bf16x8 a0 = *(const bf16x8*)(src + (size_t)r0 * 128 + ko);
        const __bf16* wb = wpack + (size_t)kt * 4096 + lane * 8;
        #pragma unroll
        for (int nt = 0; nt < 8; ++nt) {
            bf16x8 b = *(const bf16x8*)(wb + nt * 512);
            acc[nt] = __builtin_amdgcn_mfma_f32_16x16x32_bf16(a0, b, acc[nt], 0, 0, 0);
        }
    }

    #pragma unroll
    for (int r = 0; r < 4; ++r) {
        int row = rbase + quad * 4 + r;
        if (row < N_NODES) {
            #pragma unroll
            for (int nt = 0; nt < 8; ++nt) {
                float v = acc[nt][r] + bias[nt * 16 + m];
                out[(size_t)row * 128 + nt * 16 + m] = (__bf16)fmaxf(v, 0.f);
            }
        }
    }
}

// ---------------- layer 2 + UV: h2 never hits global ----------------
// Every wave: layer-2 MFMA for its 16 rows -> relu'd h2 tile -> wave-private LDS
// patch (within-wave, DS ops in-order; no barrier) -> A-frags ->
// UV = h2 @ [W3a|W3b]^T -> fp16 UV.

__global__ __launch_bounds__(256) void layer2uv_k(const __bf16* __restrict__ agg,
                                                  const __bf16* __restrict__ feat,
                                                  const __bf16* __restrict__ wpack,
                                                  const float* __restrict__ bias,
                                                  const __bf16* __restrict__ wpack4,
                                                  _Float16* __restrict__ UV) {
    __shared__ __bf16 sh[4][16][136];   // 136: rows 16B-aligned (272 B)
    int wave = threadIdx.x >> 6;
    int lane = threadIdx.x & 63;
    int m = lane & 15, q = lane >> 4;
    int rbase = blockIdx.x * 64 + wave * 16;
    int r0 = rbase + m; if (r0 > N_NODES - 1) r0 = N_NODES - 1;

    f32x4 acc[8];
    #pragma unroll
    for (int nt = 0; nt < 8; ++nt) acc[nt] = (f32x4)0.f;

    #pragma unroll
    for (int kt = 0; kt < 8; ++kt) {
        const __bf16* src = (kt < 4) ? agg : feat;
        int ko = (kt & 3) * 32 + q * 8;
        bf16x8 a0 = *(const bf16x8*)(src + (size_t)r0 * 128 + ko);
        const __bf16* wb = wpack + (size_t)kt * 4096 + lane * 8;
        #pragma unroll
        for (int nt = 0; nt < 8; ++nt) {
            bf16x8 b = *(const bf16x8*)(wb + nt * 512);
            acc[nt] = __builtin_amdgcn_mfma_f32_16x16x32_bf16(a0, b, acc[nt], 0, 0, 0);
        }
    }

    // relu'd h2 tile -> wave-private LDS (C-layout scatter)
    #pragma unroll
    for (int rr = 0; rr < 4; ++rr)
        #pragma unroll
        for (int nt = 0; nt < 8; ++nt) {
            float v = acc[nt][rr] + bias[nt * 16 + m];
            sh[wave][q * 4 + rr][nt * 16 + m] = (__bf16)fmaxf(v, 0.f);
        }

    f32x4 acc2[16];
    #pragma unroll
    for (int nt = 0; nt < 16; ++nt) acc2[nt] = (f32x4)0.f;

    #pragma unroll
    for (int kt = 0; kt < 4; ++kt) {
        bf16x8 a = *(const bf16x8*)&sh[wave][m][kt * 32 + q * 8];
        const __bf16* wb = wpack4 + (size_t)kt * 8192 + lane * 8;
        #pragma unroll
        for (int nt = 0; nt < 16; ++nt) {
            bf16x8 b = *(const bf16x8*)(wb + nt * 512);
            acc2[nt] = __builtin_amdgcn_mfma_f32_16x16x32_bf16(a, b, acc2[nt], 0, 0, 0);
        }
    }

    #pragma unroll
    for (int rr = 0; rr < 4; ++rr) {
        int row = rbase + q * 4 + rr;
        if (row < N_NODES) {
            #pragma unroll
            for (int nt = 0; nt < 16; ++nt)
                UV[(size_t)row * 256 + nt * 16 + m] = (_Float16)acc2[nt][rr];
        }
    }
}

// ---------------- pair epilogue: sigmoid(relu(U[a]+V[b]+b3) . W4 + b4) ----------------

__global__ __launch_bounds__(256) void pair_ep_k(const _Float16* __restrict__ UV,
                                                 const int* __restrict__ pairs,
                                                 const float* __restrict__ b3,
                                                 const float* __restrict__ W4,
                                                 const float* __restrict__ b4,
                                                 float* __restrict__ out) {
    int t = threadIdx.x;
    int g = t >> 4, l = t & 15;
    int base = blockIdx.x * 64;

    float4 b3a = *(const float4*)(b3 + l * 8);
    float4 b3b = *(const float4*)(b3 + l * 8 + 4);
    float4 w4a = *(const float4*)(W4 + l * 8);
    float4 w4b = *(const float4*)(W4 + l * 8 + 4);
    float bb[8] = {b3a.x, b3a.y, b3a.z, b3a.w, b3b.x, b3b.y, b3b.z, b3b.w};
    float ww[8] = {w4a.x, w4a.y, w4a.z, w4a.w, w4b.x, w4b.y, w4b.z, w4b.w};
    float b4s = b4[0];

    int2 pr[4];
    #pragma unroll
    for (int i = 0; i < 4; ++i) pr[i] = ((const int2*)pairs)[base + i * 16 + g];

    f16x8 ua[4], vb[4];
    #pragma unroll
    for (int i = 0; i < 4; ++i) {
        ua[i] = *(const f16x8*)(UV + (size_t)pr[i].x * 256 + l * 8);
        vb[i] = *(const f16x8*)(UV + (size_t)pr[i].y * 256 + 128 + l * 8);
    }

    #pragma unroll
    for (int i = 0; i < 4; ++i) {
        float p = 0.f;
        #pragma unroll
        for (int e = 0; e < 8; ++e)
            p += fmaxf((float)ua[i][e] + (float)vb[i][e] + bb[e], 0.f) * ww[e];
        #pragma unroll
        for (int s = 1; s < 16; s <<= 1) p += __shfl_xor(p, s, 64);
        if (l == 0)
            out[base + i * 16 + g] = 1.0f / (1.0f + expf(-(p + b4s)));
    }
}

// ---------------- launch ----------------

extern "C" void kernel_launch(void* const* d_in, const int* in_sizes, int n_in,
                              void* d_out, int out_size, void* d_ws, size_t ws_size,
                              hipStream_t stream) {
    const float* x   = (const float*)d_in[0];
    const int*   ei  = (const int*)d_in[1];
    const int*   prs = (const int*)d_in[2];
    const float* Wl1 = (const float*)d_in[3];
    const float* Wr1 = (const float*)d_in[4];
    const float* b1  = (const float*)d_in[5];
    const float* Wl2 = (const float*)d_in[6];
    const float* Wr2 = (const float*)d_in[7];
    const float* b2  = (const float*)d_in[8];
    const float* W3  = (const float*)d_in[9];
    const float* b3  = (const float*)d_in[10];
    const float* W4  = (const float*)d_in[11];
    const float* b4  = (const float*)d_in[12];
    float* out = (float*)d_out;

    const int* srcv = ei;
    const int* dstv = ei + E_EDGES;

    char* ws = (char*)d_ws;
    size_t off = 0;
    auto alloc = [&](size_t bytes) -> void* {
        void* p = ws + off;
        off = (off + bytes + 255) & ~(size_t)255;
        return p;
    };
    int*      fil    = (int*)alloc(sizeof(int) * N_NODES * FIL_PAD);
    int*      slots  = (int*)alloc(sizeof(int) * (size_t)N_NODES * MAX_DEG);
    __bf16*   P1     = (__bf16*)alloc(sizeof(__bf16) * 32768);
    __bf16*   P2     = (__bf16*)alloc(sizeof(__bf16) * 32768);
    __bf16*   P4     = (__bf16*)alloc(sizeof(__bf16) * 32768);
    __bf16*   xb     = (__bf16*)alloc(sizeof(__bf16) * (size_t)N_NODES * 128);
    __bf16*   aggb   = (__bf16*)alloc(sizeof(__bf16) * (size_t)N_NODES * 128);
    __bf16*   h1b    = (__bf16*)alloc(sizeof(__bf16) * (size_t)N_NODES * 128);
    _Float16* UV     = (_Float16*)alloc(sizeof(_Float16) * (size_t)N_NODES * 256);
    (void)ws_size; (void)in_sizes; (void)n_in; (void)out_size;

    hipMemsetAsync(fil, 0, sizeof(int) * N_NODES * FIL_PAD, stream);

    // prologue: conv_x || slot-fill || weight pack (independent phases)
    fused_pre_k<<<CONV_BLKS + FILL_BLKS + PREP_BLKS, 256, 0, stream>>>(
        x, xb, srcv, dstv, fil, slots, Wl1, Wr1, Wl2, Wr2, W3, P1, P2, P4);

    // layer 1
    agg1_k<<<(N_NODES + 3) / 4, 256, 0, stream>>>(xb, fil, slots, aggb);
    layer_mfma_k<<<(N_NODES + 63) / 64, 256, 0, stream>>>(aggb, xb, P1, b1, h1b);
    // layer 2 + UV (h2 stays in registers/LDS)
    agg1_k<<<(N_NODES + 3) / 4, 256, 0, stream>>>(h1b, fil, slots, aggb);
    layer2uv_k<<<(N_NODES + 63) / 64, 256, 0, stream>>>(aggb, h1b, P2, b2, P4, UV);
    // pair scoring
    pair_ep_k<<<P_PAIRS / 64, 256, 0, stream>>>(UV, prs, b3, W4, b4, out);
}

// Round 11
// 225.626 us; speedup vs baseline: 1.0255x; 1.0255x over previous
//
#include <hip/hip_runtime.h>
#include <math.h>

#define N_NODES 50000
#define E_EDGES 500000
#define P_PAIRS 200000
#define MAX_DEG 64    // Binomial(500k,1/50k): P(deg>=64) ~ 1e-28 per node

typedef __bf16    bf16x8 __attribute__((ext_vector_type(8)));
typedef _Float16  f16x8  __attribute__((ext_vector_type(8)));
typedef float     f32x4  __attribute__((ext_vector_type(4)));

// ---------------- fused prologue: conv_x  ||  slot-fill  ||  weight pack ----------------
// All three phases independent (fil pre-zeroed by memset before this kernel).
// Slot entries are uint16 (node id < 65536): halves scatter line traffic --
// R10 showed ~64B HBM write per 4B scatter entry (partial-line flush from
// non-coherent per-XCD L2s); fewer/denser lines is the only lever.
// P1/P2 (layer weights, K=256,N=128): [kt(8)][nt(8)][lane(64)][j(8)]
//   n = nt*16+(lane&15), k = kt*32+(lane>>4)*8+j ; k<128 -> Wl[n][k], else Wr[n][k-128]
// P4 (pair weights, K=128,N=256):     [kt(4)][nt(16)][lane(64)][j(8)]
//   n'= nt*16+(lane&15), k = kt*32+(lane>>4)*8+j ; n'<128 -> W3[n'][k], else W3[n'-128][128+k]

#define CONV_BLKS 6250   // N_NODES*128/4/256
#define FILL_BLKS 1954   // ceil(E/256)
#define PREP_BLKS 128    // 32768/256

__global__ __launch_bounds__(256) void fused_pre_k(
        const float* __restrict__ x, __bf16* __restrict__ xb,
        const int* __restrict__ src, const int* __restrict__ dst,
        int* __restrict__ fil, unsigned short* __restrict__ slots,
        const float* __restrict__ Wl1, const float* __restrict__ Wr1,
        const float* __restrict__ Wl2, const float* __restrict__ Wr2,
        const float* __restrict__ W3,
        __bf16* __restrict__ P1, __bf16* __restrict__ P2, __bf16* __restrict__ P4) {
    int b = blockIdx.x, t = threadIdx.x;
    if (b < CONV_BLKS) {
        int i = b * 256 + t;                      // float4 index
        float4 v = ((const float4*)x)[i];
        __bf16* o = xb + (size_t)i * 4;
        o[0] = (__bf16)v.x; o[1] = (__bf16)v.y; o[2] = (__bf16)v.z; o[3] = (__bf16)v.w;
    } else if (b < CONV_BLKS + FILL_BLKS) {
        int e = (b - CONV_BLKS) * 256 + t;
        if (e < E_EDGES) {
            int d = dst[e];
            int pos = atomicAdd(&fil[d], 1);
            if (pos < MAX_DEG)
                slots[d * MAX_DEG + pos] = (unsigned short)src[e];
        }
    } else {
        int i = (b - CONV_BLKS - FILL_BLKS) * 256 + t;   // 0..32767
        int lane = (i >> 3) & 63;
        int j = i & 7;
        int kq = (lane >> 4) * 8 + j;
        // P1/P2: K=256 layout
        {
            int kt = i >> 12, nt = (i >> 9) & 7;
            int n = nt * 16 + (lane & 15);
            int k = kt * 32 + kq;
            P1[i] = (__bf16)((k < 128) ? Wl1[n * 128 + k] : Wr1[n * 128 + (k - 128)]);
            P2[i] = (__bf16)((k < 128) ? Wl2[n * 128 + k] : Wr2[n * 128 + (k - 128)]);
        }
        // P4: K=128, N=256 layout
        {
            int kt = i >> 13, nt = (i >> 9) & 15;
            int n = nt * 16 + (lane & 15);
            int k = kt * 32 + kq;
            P4[i] = (__bf16)((n < 128) ? W3[n * 256 + k] : W3[(n - 128) * 256 + 128 + k]);
        }
    }
}

// ---------------- segment-mean aggregation: one wave per node, u16 slot table ----------------
// Coalesced 128-B neighbor-ID load; wave-uniform trip count so every
// ds_bpermute runs with full exec (inactive-lane bpermute returns 0 -- R7 bug);
// accumulation predicated per-lane. Lanes >= deg sanitize their ID to 0.

__global__ __launch_bounds__(256) void agg1_k(const __bf16* __restrict__ feat,
                                              const int* __restrict__ fil,
                                              const unsigned short* __restrict__ slots,
                                              __bf16* __restrict__ agg) {
    int n = blockIdx.x * 4 + (threadIdx.x >> 6);
    if (n >= N_NODES) return;
    int lane = threadIdx.x & 63;
    int slot = lane >> 4, l = lane & 15;
    int deg = fil[n];
    int nit = (deg < MAX_DEG) ? deg : MAX_DEG;

    int ed = (lane < nit) ? (int)slots[n * MAX_DEG + lane] : 0;  // coalesced u16

    float s[8];
    #pragma unroll
    for (int e = 0; e < 8; ++e) s[e] = 0.f;

    int trips = (nit + 3) >> 2;       // wave-uniform
    int it = slot;
    int k = 0;
    for (; k + 1 < trips; k += 2, it += 8) {
        int sn0 = __builtin_amdgcn_ds_bpermute(it << 2, ed);        // full exec
        int sn1 = __builtin_amdgcn_ds_bpermute((it + 4) << 2, ed);  // full exec
        bf16x8 v0 = *(const bf16x8*)(feat + (size_t)sn0 * 128 + l * 8);
        bf16x8 v1 = *(const bf16x8*)(feat + (size_t)sn1 * 128 + l * 8);
        if (it < nit) {
            #pragma unroll
            for (int e = 0; e < 8; ++e) s[e] += (float)v0[e];
        }
        if (it + 4 < nit) {
            #pragma unroll
            for (int e = 0; e < 8; ++e) s[e] += (float)v1[e];
        }
    }
    if (k < trips) {
        int sn = __builtin_amdgcn_ds_bpermute(it << 2, ed);         // full exec
        bf16x8 v = *(const bf16x8*)(feat + (size_t)sn * 128 + l * 8);
        if (it < nit) {
            #pragma unroll
            for (int e = 0; e < 8; ++e) s[e] += (float)v[e];
        }
    }

    // reduce the 4 slots (full exec: all lanes of the wave reach this)
    #pragma unroll
    for (int e = 0; e < 8; ++e) {
        s[e] += __shfl_xor(s[e], 16, 64);
        s[e] += __shfl_xor(s[e], 32, 64);
    }

    if (slot == 0) {
        float inv = 1.0f / fmaxf((float)deg, 1.0f);
        bf16x8 o;
        #pragma unroll
        for (int e = 0; e < 8; ++e) o[e] = (__bf16)(s[e] * inv);
        *(bf16x8*)(agg + (size_t)n * 128 + l * 8) = o;
    }
}

// ---------------- layer 1: out = relu([agg|feat] @ B + bias), 16 rows/wave ----------------

__global__ __launch_bounds__(256) void layer_mfma_k(const __bf16* __restrict__ agg,
                                                    const __bf16* __restrict__ feat,
                                                    const __bf16* __restrict__ wpack,
                                                    const float* __restrict__ bias,
                                                    __bf16* __restrict__ out) {
    int wave = threadIdx.x >> 6;
    int lane = threadIdx.x & 63;
    int m = lane & 15, quad = lane >> 4;
    int rbase = blockIdx.x * 64 + wave * 16;
    int r0 = rbase + m; if (r0 > N_NODES - 1) r0 = N_NODES - 1;

    f32x4 acc[8];
    #pragma unroll
    for (int nt = 0; nt < 8; ++nt) acc[nt] = (f32x4)0.f;

    #pragma unroll
    for (int kt = 0; kt < 8; ++kt) {
        const __bf16* src = (kt < 4) ? agg : feat;
        int ko = (kt & 3) * 32 + quad * 8;
        bf16x8 a0 = *(const bf16x8*)(src + (size_t)r0 * 128 + ko);
        const __bf16* wb = wpack + (size_t)kt * 4096 + lane * 8;
        #pragma unroll
        for (int nt = 0; nt < 8; ++nt) {
            bf16x8 b = *(const bf16x8*)(wb + nt * 512);
            acc[nt] = __builtin_amdgcn_mfma_f32_16x16x32_bf16(a0, b, acc[nt], 0, 0, 0);
        }
    }

    #pragma unroll
    for (int r = 0; r < 4; ++r) {
        int row = rbase + quad * 4 + r;
        if (row < N_NODES) {
            #pragma unroll
            for (int nt = 0; nt < 8; ++nt) {
                float v = acc[nt][r] + bias[nt * 16 + m];
                out[(size_t)row * 128 + nt * 16 + m] = (__bf16)fmaxf(v, 0.f);
            }
        }
    }
}

// ---------------- layer 2 + UV: h2 never hits global ----------------
// Every wave: layer-2 MFMA for its 16 rows -> relu'd h2 tile -> wave-private LDS
// patch (within-wave, DS ops in-order; no barrier) -> A-frags ->
// UV = h2 @ [W3a|W3b]^T -> fp16 UV.

__global__ __launch_bounds__(256) void layer2uv_k(const __bf16* __restrict__ agg,
                                                  const __bf16* __restrict__ feat,
                                                  const __bf16* __restrict__ wpack,
                                                  const float* __restrict__ bias,
                                                  const __bf16* __restrict__ wpack4,
                                                  _Float16* __restrict__ UV) {
    __shared__ __bf16 sh[4][16][136];   // 136: rows 16B-aligned (272 B)
    int wave = threadIdx.x >> 6;
    int lane = threadIdx.x & 63;
    int m = lane & 15, q = lane >> 4;
    int rbase = blockIdx.x * 64 + wave * 16;
    int r0 = rbase + m; if (r0 > N_NODES - 1) r0 = N_NODES - 1;

    f32x4 acc[8];
    #pragma unroll
    for (int nt = 0; nt < 8; ++nt) acc[nt] = (f32x4)0.f;

    #pragma unroll
    for (int kt = 0; kt < 8; ++kt) {
        const __bf16* src = (kt < 4) ? agg : feat;
        int ko = (kt & 3) * 32 + q * 8;
        bf16x8 a0 = *(const bf16x8*)(src + (size_t)r0 * 128 + ko);
        const __bf16* wb = wpack + (size_t)kt * 4096 + lane * 8;
        #pragma unroll
        for (int nt = 0; nt < 8; ++nt) {
            bf16x8 b = *(const bf16x8*)(wb + nt * 512);
            acc[nt] = __builtin_amdgcn_mfma_f32_16x16x32_bf16(a0, b, acc[nt], 0, 0, 0);
        }
    }

    // relu'd h2 tile -> wave-private LDS (C-layout scatter)
    #pragma unroll
    for (int rr = 0; rr < 4; ++rr)
        #pragma unroll
        for (int nt = 0; nt < 8; ++nt) {
            float v = acc[nt][rr] + bias[nt * 16 + m];
            sh[wave][q * 4 + rr][nt * 16 + m] = (__bf16)fmaxf(v, 0.f);
        }

    f32x4 acc2[16];
    #pragma unroll
    for (int nt = 0; nt < 16; ++nt) acc2[nt] = (f32x4)0.f;

    #pragma unroll
    for (int kt = 0; kt < 4; ++kt) {
        bf16x8 a = *(const bf16x8*)&sh[wave][m][kt * 32 + q * 8];
        const __bf16* wb = wpack4 + (size_t)kt * 8192 + lane * 8;
        #pragma unroll
        for (int nt = 0; nt < 16; ++nt) {
            bf16x8 b = *(const bf16x8*)(wb + nt * 512);
            acc2[nt] = __builtin_amdgcn_mfma_f32_16x16x32_bf16(a, b, acc2[nt], 0, 0, 0);
        }
    }

    #pragma unroll
    for (int rr = 0; rr < 4; ++rr) {
        int row = rbase + q * 4 + rr;
        if (row < N_NODES) {
            #pragma unroll
            for (int nt = 0; nt < 16; ++nt)
                UV[(size_t)row * 256 + nt * 16 + m] = (_Float16)acc2[nt][rr];
        }
    }
}

// ---------------- pair epilogue: sigmoid(relu(U[a]+V[b]+b3) . W4 + b4) ----------------

__global__ __launch_bounds__(256) void pair_ep_k(const _Float16* __restrict__ UV,
                                                 const int* __restrict__ pairs,
                                                 const float* __restrict__ b3,
                                                 const float* __restrict__ W4,
                                                 const float* __restrict__ b4,
                                                 float* __restrict__ out) {
    int t = threadIdx.x;
    int g = t >> 4, l = t & 15;
    int base = blockIdx.x * 64;

    float4 b3a = *(const float4*)(b3 + l * 8);
    float4 b3b = *(const float4*)(b3 + l * 8 + 4);
    float4 w4a = *(const float4*)(W4 + l * 8);
    float4 w4b = *(const float4*)(W4 + l * 8 + 4);
    float bb[8] = {b3a.x, b3a.y, b3a.z, b3a.w, b3b.x, b3b.y, b3b.z, b3b.w};
    float ww[8] = {w4a.x, w4a.y, w4a.z, w4a.w, w4b.x, w4b.y, w4b.z, w4b.w};
    float b4s = b4[0];

    int2 pr[4];
    #pragma unroll
    for (int i = 0; i < 4; ++i) pr[i] = ((const int2*)pairs)[base + i * 16 + g];

    f16x8 ua[4], vb[4];
    #pragma unroll
    for (int i = 0; i < 4; ++i) {
        ua[i] = *(const f16x8*)(UV + (size_t)pr[i].x * 256 + l * 8);
        vb[i] = *(const f16x8*)(UV + (size_t)pr[i].y * 256 + 128 + l * 8);
    }

    #pragma unroll
    for (int i = 0; i < 4; ++i) {
        float p = 0.f;
        #pragma unroll
        for (int e = 0; e < 8; ++e)
            p += fmaxf((float)ua[i][e] + (float)vb[i][e] + bb[e], 0.f) * ww[e];
        #pragma unroll
        for (int s = 1; s < 16; s <<= 1) p += __shfl_xor(p, s, 64);
        if (l == 0)
            out[base + i * 16 + g] = 1.0f / (1.0f + expf(-(p + b4s)));
    }
}

// ---------------- launch ----------------

extern "C" void kernel_launch(void* const* d_in, const int* in_sizes, int n_in,
                              void* d_out, int out_size, void* d_ws, size_t ws_size,
                              hipStream_t stream) {
    const float* x   = (const float*)d_in[0];
    const int*   ei  = (const int*)d_in[1];
    const int*   prs = (const int*)d_in[2];
    const float* Wl1 = (const float*)d_in[3];
    const float* Wr1 = (const float*)d_in[4];
    const float* b1  = (const float*)d_in[5];
    const float* Wl2 = (const float*)d_in[6];
    const float* Wr2 = (const float*)d_in[7];
    const float* b2  = (const float*)d_in[8];
    const float* W3  = (const float*)d_in[9];
    const float* b3  = (const float*)d_in[10];
    const float* W4  = (const float*)d_in[11];
    const float* b4  = (const float*)d_in[12];
    float* out = (float*)d_out;

    const int* srcv = ei;
    const int* dstv = ei + E_EDGES;

    char* ws = (char*)d_ws;
    size_t off = 0;
    auto alloc = [&](size_t bytes) -> void* {
        void* p = ws + off;
        off = (off + bytes + 255) & ~(size_t)255;
        return p;
    };
    int*            fil    = (int*)alloc(sizeof(int) * N_NODES);
    unsigned short* slots  = (unsigned short*)alloc(sizeof(unsigned short) * (size_t)N_NODES * MAX_DEG);
    __bf16*   P1     = (__bf16*)alloc(sizeof(__bf16) * 32768);
    __bf16*   P2     = (__bf16*)alloc(sizeof(__bf16) * 32768);
    __bf16*   P4     = (__bf16*)alloc(sizeof(__bf16) * 32768);
    __bf16*   xb     = (__bf16*)alloc(sizeof(__bf16) * (size_t)N_NODES * 128);
    __bf16*   aggb   = (__bf16*)alloc(sizeof(__bf16) * (size_t)N_NODES * 128);
    __bf16*   h1b    = (__bf16*)alloc(sizeof(__bf16) * (size_t)N_NODES * 128);
    _Float16* UV     = (_Float16*)alloc(sizeof(_Float16) * (size_t)N_NODES * 256);
    (void)ws_size; (void)in_sizes; (void)n_in; (void)out_size;

    hipMemsetAsync(fil, 0, sizeof(int) * N_NODES, stream);

    // prologue: conv_x || slot-fill || weight pack (independent phases)
    fused_pre_k<<<CONV_BLKS + FILL_BLKS + PREP_BLKS, 256, 0, stream>>>(
        x, xb, srcv, dstv, fil, slots, Wl1, Wr1, Wl2, Wr2, W3, P1, P2, P4);

    // layer 1
    agg1_k<<<(N_NODES + 3) / 4, 256, 0, stream>>>(xb, fil, slots, aggb);
    layer_mfma_k<<<(N_NODES + 63) / 64, 256, 0, stream>>>(aggb, xb, P1, b1, h1b);
    // layer 2 + UV (h2 stays in registers/LDS)
    agg1_k<<<(N_NODES + 3) / 4, 256, 0, stream>>>(h1b, fil, slots, aggb);
    layer2uv_k<<<(N_NODES + 63) / 64, 256, 0, stream>>>(aggb, h1b, P2, b2, P4, UV);
    // pair scoring
    pair_ep_k<<<P_PAIRS / 64, 256, 0, stream>>>(UV, prs, b3, W4, b4, out);
}

// Round 12
// 221.867 us; speedup vs baseline: 1.0429x; 1.0169x over previous
//
#include <hip/hip_runtime.h>
#include <math.h>

#define N_NODES 50000
#define E_EDGES 500000
#define P_PAIRS 200000
#define MAX_DEG 64    // Binomial(500k,1/50k): P(deg>=64) ~ 1e-28 per node

#define NB        196   // buckets: bucket(d) = d >> 8 (256 nodes each), 49999>>8 = 195
#define EB        4096  // edges per sort block
#define EPT       16    // edges per thread (256 thr)
#define SORT_BLKS 123   // ceil(500000/4096)

typedef __bf16    bf16x8 __attribute__((ext_vector_type(8)));
typedef _Float16  f16x8  __attribute__((ext_vector_type(8)));
typedef float     f32x4  __attribute__((ext_vector_type(4)));

// ---------------- K1: bucket-count  ||  conv_x  ||  weight pack ----------------
// R11 post-mortem: 500k returning global atomics + 500k random scatters are
// fabric-transaction-throughput bound (~40us regardless of padding/dtype).
// This pipeline replaces them with an LDS counting sort: 24k global atomics,
// dense writes. Phases below are independent (bucketCnt pre-zeroed by memset).

#define CONV_BLKS 6250   // N_NODES*128/4/256
#define PREP_BLKS 128    // 32768/256

__global__ __launch_bounds__(256) void pre_k(
        const float* __restrict__ x, __bf16* __restrict__ xb,
        const int* __restrict__ dst,
        int* __restrict__ bucketCnt, int* __restrict__ blockBase,
        const float* __restrict__ Wl1, const float* __restrict__ Wr1,
        const float* __restrict__ Wl2, const float* __restrict__ Wr2,
        const float* __restrict__ W3,
        __bf16* __restrict__ P1, __bf16* __restrict__ P2, __bf16* __restrict__ P4) {
    __shared__ int cnt[NB];
    int b = blockIdx.x, t = threadIdx.x;
    if (b < SORT_BLKS) {
        if (t < NB) cnt[t] = 0;
        __syncthreads();
        int ebase = b * EB;
        #pragma unroll
        for (int i = 0; i < EPT; ++i) {
            int e = ebase + i * 256 + t;
            if (e < E_EDGES) atomicAdd(&cnt[dst[e] >> 8], 1);
        }
        __syncthreads();
        if (t < NB) blockBase[b * NB + t] = atomicAdd(&bucketCnt[t], cnt[t]);
    } else if (b < SORT_BLKS + CONV_BLKS) {
        int i = (b - SORT_BLKS) * 256 + t;        // float4 index
        float4 v = ((const float4*)x)[i];
        __bf16* o = xb + (size_t)i * 4;
        o[0] = (__bf16)v.x; o[1] = (__bf16)v.y; o[2] = (__bf16)v.z; o[3] = (__bf16)v.w;
    } else {
        int i = (b - SORT_BLKS - CONV_BLKS) * 256 + t;   // 0..32767
        int lane = (i >> 3) & 63;
        int j = i & 7;
        int kq = (lane >> 4) * 8 + j;
        {   // P1/P2: K=256 layout
            int kt = i >> 12, nt = (i >> 9) & 7;
            int n = nt * 16 + (lane & 15);
            int k = kt * 32 + kq;
            P1[i] = (__bf16)((k < 128) ? Wl1[n * 128 + k] : Wr1[n * 128 + (k - 128)]);
            P2[i] = (__bf16)((k < 128) ? Wl2[n * 128 + k] : Wr2[n * 128 + (k - 128)]);
        }
        {   // P4: K=128, N=256 layout
            int kt = i >> 13, nt = (i >> 9) & 15;
            int n = nt * 16 + (lane & 15);
            int k = kt * 32 + kq;
            P4[i] = (__bf16)((n < 128) ? W3[n * 256 + k] : W3[(n - 128) * 256 + 128 + k]);
        }
    }
}

// ---------------- K2: exclusive scan of bucket totals (1 block) ----------------

__global__ __launch_bounds__(256) void scan_k(const int* __restrict__ bucketCnt,
                                              int* __restrict__ bucketBase) {
    __shared__ int buf[256];
    int t = threadIdx.x;
    int v = (t < NB) ? bucketCnt[t] : 0;
    buf[t] = v;
    __syncthreads();
    for (int off = 1; off < 256; off <<= 1) {
        int xv = (t >= off) ? buf[t - off] : 0;
        __syncthreads();
        buf[t] += xv;
        __syncthreads();
    }
    if (t < NB) bucketBase[t] = buf[t] - v;
}

// ---------------- K3: place edges into bucket-sorted edgebuf (staged in LDS) ----------------
// packed = (dst<<16)|src (both < 65536). Stream-out is coalesced within runs.

__global__ __launch_bounds__(256) void place_k(const int* __restrict__ src,
                                               const int* __restrict__ dst,
                                               const int* __restrict__ bucketBase,
                                               const int* __restrict__ blockBase,
                                               unsigned* __restrict__ edgebuf) {
    __shared__ int cnt[256];
    __shared__ int buf[256];
    __shared__ int sbase[NB];
    __shared__ int gbase[NB];
    __shared__ int cur[NB];
    __shared__ unsigned sortbuf[EB];
    __shared__ unsigned char bktof[EB];
    int blk = blockIdx.x, t = threadIdx.x;
    cnt[t] = 0;
    if (t < NB) cur[t] = 0;
    __syncthreads();

    unsigned packed[EPT];
    int bk[EPT];
    int ebase = blk * EB;
    #pragma unroll
    for (int i = 0; i < EPT; ++i) {
        int e = ebase + i * 256 + t;
        if (e < E_EDGES) {
            int d = dst[e];
            packed[i] = ((unsigned)d << 16) | (unsigned)src[e];
            bk[i] = d >> 8;
            atomicAdd(&cnt[bk[i]], 1);
        } else bk[i] = -1;
    }
    __syncthreads();

    // block-local exclusive scan of cnt
    int v = cnt[t];
    buf[t] = v;
    __syncthreads();
    for (int off = 1; off < 256; off <<= 1) {
        int xv = (t >= off) ? buf[t - off] : 0;
        __syncthreads();
        buf[t] += xv;
        __syncthreads();
    }
    if (t < NB) {
        sbase[t] = buf[t] - v;
        gbase[t] = bucketBase[t] + blockBase[blk * NB + t];
    }
    __syncthreads();

    #pragma unroll
    for (int i = 0; i < EPT; ++i) {
        if (bk[i] >= 0) {
            int p = sbase[bk[i]] + atomicAdd(&cur[bk[i]], 1);
            sortbuf[p] = packed[i];
            bktof[p] = (unsigned char)bk[i];
        }
    }
    __syncthreads();

    int nE = E_EDGES - ebase; if (nE > EB) nE = EB;
    for (int i = t; i < nE; i += 256) {
        int bb = bktof[i];
        edgebuf[gbase[bb] + (i - sbase[bb])] = sortbuf[i];
    }
}

// ---------------- K4: build slot rows per bucket in LDS, dense writeout ----------------
// srow garbage beyond deg is harmless: agg masks lanes >= deg.

__global__ __launch_bounds__(256) void slots_k(const unsigned* __restrict__ edgebuf,
                                               const int* __restrict__ bucketCnt,
                                               const int* __restrict__ bucketBase,
                                               unsigned short* __restrict__ slots,
                                               int* __restrict__ deg) {
    __shared__ unsigned short srow[256 * MAX_DEG];   // 32 KB
    __shared__ int cur[256];
    int b = blockIdx.x, t = threadIdx.x;
    cur[t] = 0;
    __syncthreads();
    int base = bucketBase[b], n = bucketCnt[b];
    for (int i = t; i < n; i += 256) {
        unsigned p = edgebuf[base + i];
        int dl = (p >> 16) & 255;
        int pos = atomicAdd(&cur[dl], 1);
        if (pos < MAX_DEG) srow[dl * MAX_DEG + pos] = (unsigned short)(p & 0xFFFFu);
    }
    __syncthreads();
    // dense 32KB writeout as u32
    unsigned* sl32 = (unsigned*)slots;
    const unsigned* sr32 = (const unsigned*)srow;
    int gbase32 = b * 8192;                          // 256 rows * 32 u32
    for (int i = t; i < 8192; i += 256) {
        int node = b * 256 + (i >> 5);
        if (node < N_NODES) sl32[gbase32 + i] = sr32[i];
    }
    int node = b * 256 + t;
    if (node < N_NODES) deg[node] = cur[t];
}

// ---------------- segment-mean aggregation: one wave per node, u16 slot table ----------------
// Wave-uniform trip count so every ds_bpermute runs with full exec (R7 bug);
// accumulation predicated per-lane. Lanes >= deg sanitize their ID to 0.

__global__ __launch_bounds__(256) void agg1_k(const __bf16* __restrict__ feat,
                                              const int* __restrict__ deg_a,
                                              const unsigned short* __restrict__ slots,
                                              __bf16* __restrict__ agg) {
    int n = blockIdx.x * 4 + (threadIdx.x >> 6);
    if (n >= N_NODES) return;
    int lane = threadIdx.x & 63;
    int slot = lane >> 4, l = lane & 15;
    int deg = deg_a[n];
    int nit = (deg < MAX_DEG) ? deg : MAX_DEG;

    int ed = (lane < nit) ? (int)slots[n * MAX_DEG + lane] : 0;  // coalesced u16

    float s[8];
    #pragma unroll
    for (int e = 0; e < 8; ++e) s[e] = 0.f;

    int trips = (nit + 3) >> 2;       // wave-uniform
    int it = slot;
    int k = 0;
    for (; k + 1 < trips; k += 2, it += 8) {
        int sn0 = __builtin_amdgcn_ds_bpermute(it << 2, ed);        // full exec
        int sn1 = __builtin_amdgcn_ds_bpermute((it + 4) << 2, ed);  // full exec
        bf16x8 v0 = *(const bf16x8*)(feat + (size_t)sn0 * 128 + l * 8);
        bf16x8 v1 = *(const bf16x8*)(feat + (size_t)sn1 * 128 + l * 8);
        if (it < nit) {
            #pragma unroll
            for (int e = 0; e < 8; ++e) s[e] += (float)v0[e];
        }
        if (it + 4 < nit) {
            #pragma unroll
            for (int e = 0; e < 8; ++e) s[e] += (float)v1[e];
        }
    }
    if (k < trips) {
        int sn = __builtin_amdgcn_ds_bpermute(it << 2, ed);         // full exec
        bf16x8 v = *(const bf16x8*)(feat + (size_t)sn * 128 + l * 8);
        if (it < nit) {
            #pragma unroll
            for (int e = 0; e < 8; ++e) s[e] += (float)v[e];
        }
    }

    #pragma unroll
    for (int e = 0; e < 8; ++e) {
        s[e] += __shfl_xor(s[e], 16, 64);
        s[e] += __shfl_xor(s[e], 32, 64);
    }

    if (slot == 0) {
        float inv = 1.0f / fmaxf((float)deg, 1.0f);
        bf16x8 o;
        #pragma unroll
        for (int e = 0; e < 8; ++e) o[e] = (__bf16)(s[e] * inv);
        *(bf16x8*)(agg + (size_t)n * 128 + l * 8) = o;
    }
}

// ---------------- layer 1: out = relu([agg|feat] @ B + bias), 16 rows/wave ----------------

__global__ __launch_bounds__(256) void layer_mfma_k(const __bf16* __restrict__ agg,
                                                    const __bf16* __restrict__ feat,
                                                    const __bf16* __restrict__ wpack,
                                                    const float* __restrict__ bias,
                                                    __bf16* __restrict__ out) {
    int wave = threadIdx.x >> 6;
    int lane = threadIdx.x & 63;
    int m = lane & 15, quad = lane >> 4;
    int rbase = blockIdx.x * 64 + wave * 16;
    int r0 = rbase + m; if (r0 > N_NODES - 1) r0 = N_NODES - 1;

    f32x4 acc[8];
    #pragma unroll
    for (int nt = 0; nt < 8; ++nt) acc[nt] = (f32x4)0.f;

    #pragma unroll
    for (int kt = 0; kt < 8; ++kt) {
        const __bf16* src = (kt < 4) ? agg : feat;
        int ko = (kt & 3) * 32 + quad * 8;
        bf16x8 a0 = *(const bf16x8*)(src + (size_t)r0 * 128 + ko);
        const __bf16* wb = wpack + (size_t)kt * 4096 + lane * 8;
        #pragma unroll
        for (int nt = 0; nt < 8; ++nt) {
            bf16x8 b = *(const bf16x8*)(wb + nt * 512);
            acc[nt] = __builtin_amdgcn_mfma_f32_16x16x32_bf16(a0, b, acc[nt], 0, 0, 0);
        }
    }

    #pragma unroll
    for (int r = 0; r < 4; ++r) {
        int row = rbase + quad * 4 + r;
        if (row < N_NODES) {
            #pragma unroll
            for (int nt = 0; nt < 8; ++nt) {
                float v = acc[nt][r] + bias[nt * 16 + m];
                out[(size_t)row * 128 + nt * 16 + m] = (__bf16)fmaxf(v, 0.f);
            }
        }
    }
}

// ---------------- layer 2 + UV: h2 never hits global ----------------

__global__ __launch_bounds__(256) void layer2uv_k(const __bf16* __restrict__ agg,
                                                  const __bf16* __restrict__ feat,
                                                  const __bf16* __restrict__ wpack,
                                                  const float* __restrict__ bias,
                                                  const __bf16* __restrict__ wpack4,
                                                  _Float16* __restrict__ UV) {
    __shared__ __bf16 sh[4][16][136];   // 136: rows 16B-aligned (272 B)
    int wave = threadIdx.x >> 6;
    int lane = threadIdx.x & 63;
    int m = lane & 15, q = lane >> 4;
    int rbase = blockIdx.x * 64 + wave * 16;
    int r0 = rbase + m; if (r0 > N_NODES - 1) r0 = N_NODES - 1;

    f32x4 acc[8];
    #pragma unroll
    for (int nt = 0; nt < 8; ++nt) acc[nt] = (f32x4)0.f;

    #pragma unroll
    for (int kt = 0; kt < 8; ++kt) {
        const __bf16* src = (kt < 4) ? agg : feat;
        int ko = (kt & 3) * 32 + q * 8;
        bf16x8 a0 = *(const bf16x8*)(src + (size_t)r0 * 128 + ko);
        const __bf16* wb = wpack + (size_t)kt * 4096 + lane * 8;
        #pragma unroll
        for (int nt = 0; nt < 8; ++nt) {
            bf16x8 b = *(const bf16x8*)(wb + nt * 512);
            acc[nt] = __builtin_amdgcn_mfma_f32_16x16x32_bf16(a0, b, acc[nt], 0, 0, 0);
        }
    }

    // relu'd h2 tile -> wave-private LDS (C-layout scatter, within-wave only)
    #pragma unroll
    for (int rr = 0; rr < 4; ++rr)
        #pragma unroll
        for (int nt = 0; nt < 8; ++nt) {
            float v = acc[nt][rr] + bias[nt * 16 + m];
            sh[wave][q * 4 + rr][nt * 16 + m] = (__bf16)fmaxf(v, 0.f);
        }

    f32x4 acc2[16];
    #pragma unroll
    for (int nt = 0; nt < 16; ++nt) acc2[nt] = (f32x4)0.f;

    #pragma unroll
    for (int kt = 0; kt < 4; ++kt) {
        bf16x8 a = *(const bf16x8*)&sh[wave][m][kt * 32 + q * 8];
        const __bf16* wb = wpack4 + (size_t)kt * 8192 + lane * 8;
        #pragma unroll
        for (int nt = 0; nt < 16; ++nt) {
            bf16x8 b = *(const bf16x8*)(wb + nt * 512);
            acc2[nt] = __builtin_amdgcn_mfma_f32_16x16x32_bf16(a, b, acc2[nt], 0, 0, 0);
        }
    }

    #pragma unroll
    for (int rr = 0; rr < 4; ++rr) {
        int row = rbase + q * 4 + rr;
        if (row < N_NODES) {
            #pragma unroll
            for (int nt = 0; nt < 16; ++nt)
                UV[(size_t)row * 256 + nt * 16 + m] = (_Float16)acc2[nt][rr];
        }
    }
}

// ---------------- pair epilogue: sigmoid(relu(U[a]+V[b]+b3) . W4 + b4) ----------------

__global__ __launch_bounds__(256) void pair_ep_k(const _Float16* __restrict__ UV,
                                                 const int* __restrict__ pairs,
                                                 const float* __restrict__ b3,
                                                 const float* __restrict__ W4,
                                                 const float* __restrict__ b4,
                                                 float* __restrict__ out) {
    int t = threadIdx.x;
    int g = t >> 4, l = t & 15;
    int base = blockIdx.x * 64;

    float4 b3a = *(const float4*)(b3 + l * 8);
    float4 b3b = *(const float4*)(b3 + l * 8 + 4);
    float4 w4a = *(const float4*)(W4 + l * 8);
    float4 w4b = *(const float4*)(W4 + l * 8 + 4);
    float bb[8] = {b3a.x, b3a.y, b3a.z, b3a.w, b3b.x, b3b.y, b3b.z, b3b.w};
    float ww[8] = {w4a.x, w4a.y, w4a.z, w4a.w, w4b.x, w4b.y, w4b.z, w4b.w};
    float b4s = b4[0];

    int2 pr[4];
    #pragma unroll
    for (int i = 0; i < 4; ++i) pr[i] = ((const int2*)pairs)[base + i * 16 + g];

    f16x8 ua[4], vb[4];
    #pragma unroll
    for (int i = 0; i < 4; ++i) {
        ua[i] = *(const f16x8*)(UV + (size_t)pr[i].x * 256 + l * 8);
        vb[i] = *(const f16x8*)(UV + (size_t)pr[i].y * 256 + 128 + l * 8);
    }

    #pragma unroll
    for (int i = 0; i < 4; ++i) {
        float p = 0.f;
        #pragma unroll
        for (int e = 0; e < 8; ++e)
            p += fmaxf((float)ua[i][e] + (float)vb[i][e] + bb[e], 0.f) * ww[e];
        #pragma unroll
        for (int s = 1; s < 16; s <<= 1) p += __shfl_xor(p, s, 64);
        if (l == 0)
            out[base + i * 16 + g] = 1.0f / (1.0f + expf(-(p + b4s)));
    }
}

// ---------------- launch ----------------

extern "C" void kernel_launch(void* const* d_in, const int* in_sizes, int n_in,
                              void* d_out, int out_size, void* d_ws, size_t ws_size,
                              hipStream_t stream) {
    const float* x   = (const float*)d_in[0];
    const int*   ei  = (const int*)d_in[1];
    const int*   prs = (const int*)d_in[2];
    const float* Wl1 = (const float*)d_in[3];
    const float* Wr1 = (const float*)d_in[4];
    const float* b1  = (const float*)d_in[5];
    const float* Wl2 = (const float*)d_in[6];
    const float* Wr2 = (const float*)d_in[7];
    const float* b2  = (const float*)d_in[8];
    const float* W3  = (const float*)d_in[9];
    const float* b3  = (const float*)d_in[10];
    const float* W4  = (const float*)d_in[11];
    const float* b4  = (const float*)d_in[12];
    float* out = (float*)d_out;

    const int* srcv = ei;
    const int* dstv = ei + E_EDGES;

    char* ws = (char*)d_ws;
    size_t off = 0;
    auto alloc = [&](size_t bytes) -> void* {
        void* p = ws + off;
        off = (off + bytes + 255) & ~(size_t)255;
        return p;
    };
    int*            bucketCnt  = (int*)alloc(sizeof(int) * NB);
    int*            bucketBase = (int*)alloc(sizeof(int) * NB);
    int*            blockBase  = (int*)alloc(sizeof(int) * SORT_BLKS * NB);
    unsigned*       edgebuf    = (unsigned*)alloc(sizeof(unsigned) * E_EDGES);
    int*            deg        = (int*)alloc(sizeof(int) * N_NODES);
    unsigned short* slots      = (unsigned short*)alloc(sizeof(unsigned short) * (size_t)N_NODES * MAX_DEG + 512);
    __bf16*   P1     = (__bf16*)alloc(sizeof(__bf16) * 32768);
    __bf16*   P2     = (__bf16*)alloc(sizeof(__bf16) * 32768);
    __bf16*   P4     = (__bf16*)alloc(sizeof(__bf16) * 32768);
    __bf16*   xb     = (__bf16*)alloc(sizeof(__bf16) * (size_t)N_NODES * 128);
    __bf16*   aggb   = (__bf16*)alloc(sizeof(__bf16) * (size_t)N_NODES * 128);
    __bf16*   h1b    = (__bf16*)alloc(sizeof(__bf16) * (size_t)N_NODES * 128);
    _Float16* UV     = (_Float16*)alloc(sizeof(_Float16) * (size_t)N_NODES * 256);
    (void)ws_size; (void)in_sizes; (void)n_in; (void)out_size;

    hipMemsetAsync(bucketCnt, 0, sizeof(int) * NB, stream);

    // K1: bucket-count || conv_x || weight pack
    pre_k<<<SORT_BLKS + CONV_BLKS + PREP_BLKS, 256, 0, stream>>>(
        x, xb, dstv, bucketCnt, blockBase, Wl1, Wr1, Wl2, Wr2, W3, P1, P2, P4);
    // K2: bucket base scan
    scan_k<<<1, 256, 0, stream>>>(bucketCnt, bucketBase);
    // K3: place edges (bucket-sorted, coalesced)
    place_k<<<SORT_BLKS, 256, 0, stream>>>(srcv, dstv, bucketBase, blockBase, edgebuf);
    // K4: build slot rows + deg (dense writes, LDS atomics only)
    slots_k<<<NB, 256, 0, stream>>>(edgebuf, bucketCnt, bucketBase, slots, deg);

    // layer 1
    agg1_k<<<(N_NODES + 3) / 4, 256, 0, stream>>>(xb, deg, slots, aggb);
    layer_mfma_k<<<(N_NODES + 63) / 64, 256, 0, stream>>>(aggb, xb, P1, b1, h1b);
    // layer 2 + UV (h2 stays in registers/LDS)
    agg1_k<<<(N_NODES + 3) / 4, 256, 0, stream>>>(h1b, deg, slots, aggb);
    layer2uv_k<<<(N_NODES + 63) / 64, 256, 0, stream>>>(aggb, h1b, P2, b2, P4, UV);
    // pair scoring
    pair_ep_k<<<P_PAIRS / 64, 256, 0, stream>>>(UV, prs, b3, W4, b4, out);
}

// Round 13
// 216.968 us; speedup vs baseline: 1.0665x; 1.0226x over previous
//
#include <hip/hip_runtime.h>
#include <math.h>

#define N_NODES 50000
#define E_EDGES 500000
#define P_PAIRS 200000
#define MAX_DEG 64    // Binomial(500k,1/50k): P(deg>=64) ~ 1e-28 per node

#define NB        196   // buckets: bucket(d) = d >> 8 (256 nodes each)
#define EB        2048  // edges per sort block (R13: halved -> 2x blocks, shorter serial path)
#define EPT       8     // edges per thread (256 thr)
#define SORT_BLKS 245   // ceil(500000/2048)

typedef __bf16    bf16x8 __attribute__((ext_vector_type(8)));
typedef _Float16  f16x8  __attribute__((ext_vector_type(8)));
typedef float     f32x4  __attribute__((ext_vector_type(4)));

// ---------------- K1: bucket-count  ||  conv_x  ||  weight pack ----------------
// Counting-sort prologue (R12): 48k global atomics vs 500k, dense writes.
// Phases independent; bucketCnt pre-zeroed by memset.

#define CONV_BLKS 1563   // ceil(N_NODES*128/4 / 1024): 4 float4 per thread
#define PREP_BLKS 128    // 32768/256

__global__ __launch_bounds__(256) void pre_k(
        const float* __restrict__ x, __bf16* __restrict__ xb,
        const int* __restrict__ dst,
        int* __restrict__ bucketCnt, int* __restrict__ blockBase,
        const float* __restrict__ Wl1, const float* __restrict__ Wr1,
        const float* __restrict__ Wl2, const float* __restrict__ Wr2,
        const float* __restrict__ W3,
        __bf16* __restrict__ P1, __bf16* __restrict__ P2, __bf16* __restrict__ P4) {
    __shared__ int cnt[NB];
    int b = blockIdx.x, t = threadIdx.x;
    if (b < SORT_BLKS) {
        if (t < NB) cnt[t] = 0;
        __syncthreads();
        int ebase = b * EB;
        #pragma unroll
        for (int i = 0; i < EPT; ++i) {
            int e = ebase + i * 256 + t;
            if (e < E_EDGES) atomicAdd(&cnt[dst[e] >> 8], 1);
        }
        __syncthreads();
        if (t < NB) blockBase[b * NB + t] = atomicAdd(&bucketCnt[t], cnt[t]);
    } else if (b < SORT_BLKS + CONV_BLKS) {
        int i0 = (b - SORT_BLKS) * 1024 + t;      // float4 index, 4 per thread
        #pragma unroll
        for (int k = 0; k < 4; ++k) {
            int i = i0 + k * 256;
            if (i < N_NODES * 128 / 4) {
                float4 v = ((const float4*)x)[i];
                __bf16* o = xb + (size_t)i * 4;
                o[0] = (__bf16)v.x; o[1] = (__bf16)v.y; o[2] = (__bf16)v.z; o[3] = (__bf16)v.w;
            }
        }
    } else {
        int i = (b - SORT_BLKS - CONV_BLKS) * 256 + t;   // 0..32767
        int lane = (i >> 3) & 63;
        int j = i & 7;
        int kq = (lane >> 4) * 8 + j;
        {   // P1/P2: K=256 layout
            int kt = i >> 12, nt = (i >> 9) & 7;
            int n = nt * 16 + (lane & 15);
            int k = kt * 32 + kq;
            P1[i] = (__bf16)((k < 128) ? Wl1[n * 128 + k] : Wr1[n * 128 + (k - 128)]);
            P2[i] = (__bf16)((k < 128) ? Wl2[n * 128 + k] : Wr2[n * 128 + (k - 128)]);
        }
        {   // P4: K=128, N=256 layout
            int kt = i >> 13, nt = (i >> 9) & 15;
            int n = nt * 16 + (lane & 15);
            int k = kt * 32 + kq;
            P4[i] = (__bf16)((n < 128) ? W3[n * 256 + k] : W3[(n - 128) * 256 + 128 + k]);
        }
    }
}

// ---------------- K2: place edges into bucket-sorted edgebuf (staged in LDS) ----------------
// Bucket prefix computed in-block (196-elem scan) -- no separate scan kernel.
// packed = (dst<<16)|src (both < 65536).

__global__ __launch_bounds__(256) void place_k(const int* __restrict__ src,
                                               const int* __restrict__ dst,
                                               const int* __restrict__ bucketCnt,
                                               const int* __restrict__ blockBase,
                                               unsigned* __restrict__ edgebuf) {
    __shared__ int cnt[256];
    __shared__ int buf[256];
    __shared__ int sbase[NB];
    __shared__ int gbase[NB];
    __shared__ int cur[NB];
    __shared__ unsigned sortbuf[EB];
    __shared__ unsigned char bktof[EB];
    int blk = blockIdx.x, t = threadIdx.x;

    // bucket base prefix (exclusive scan of bucketCnt)
    int bv = (t < NB) ? bucketCnt[t] : 0;
    buf[t] = bv;
    __syncthreads();
    for (int off = 1; off < 256; off <<= 1) {
        int xv = (t >= off) ? buf[t - off] : 0;
        __syncthreads();
        buf[t] += xv;
        __syncthreads();
    }
    if (t < NB) gbase[t] = (buf[t] - bv) + blockBase[blk * NB + t];
    cnt[t] = 0;
    if (t < NB) cur[t] = 0;
    __syncthreads();

    unsigned packed[EPT];
    int bk[EPT];
    int ebase = blk * EB;
    #pragma unroll
    for (int i = 0; i < EPT; ++i) {
        int e = ebase + i * 256 + t;
        if (e < E_EDGES) {
            int d = dst[e];
            packed[i] = ((unsigned)d << 16) | (unsigned)src[e];
            bk[i] = d >> 8;
            atomicAdd(&cnt[bk[i]], 1);
        } else bk[i] = -1;
    }
    __syncthreads();

    // block-local exclusive scan of cnt
    int v = cnt[t];
    buf[t] = v;
    __syncthreads();
    for (int off = 1; off < 256; off <<= 1) {
        int xv = (t >= off) ? buf[t - off] : 0;
        __syncthreads();
        buf[t] += xv;
        __syncthreads();
    }
    if (t < NB) sbase[t] = buf[t] - v;
    __syncthreads();

    #pragma unroll
    for (int i = 0; i < EPT; ++i) {
        if (bk[i] >= 0) {
            int p = sbase[bk[i]] + atomicAdd(&cur[bk[i]], 1);
            sortbuf[p] = packed[i];
            bktof[p] = (unsigned char)bk[i];
        }
    }
    __syncthreads();

    int nE = E_EDGES - ebase; if (nE > EB) nE = EB;
    for (int i = t; i < nE; i += 256) {
        int bb = bktof[i];
        edgebuf[gbase[bb] + (i - sbase[bb])] = sortbuf[i];
    }
}

// ---------------- K3: build slot rows per bucket in LDS, dense writeout ----------------
// Bucket base computed in-block. srow garbage beyond deg is harmless (agg masks).

__global__ __launch_bounds__(256) void slots_k(const unsigned* __restrict__ edgebuf,
                                               const int* __restrict__ bucketCnt,
                                               unsigned short* __restrict__ slots,
                                               int* __restrict__ deg) {
    __shared__ unsigned short srow[256 * MAX_DEG];   // 32 KB
    __shared__ int cur[256];
    __shared__ int buf[256];
    __shared__ int sc[2];
    int b = blockIdx.x, t = threadIdx.x;

    int bv = (t < NB) ? bucketCnt[t] : 0;
    buf[t] = bv;
    cur[t] = 0;
    __syncthreads();
    for (int off = 1; off < 256; off <<= 1) {
        int xv = (t >= off) ? buf[t - off] : 0;
        __syncthreads();
        buf[t] += xv;
        __syncthreads();
    }
    if (t == b) { sc[0] = buf[t] - bv; sc[1] = bv; }
    __syncthreads();
    int base = sc[0], n = sc[1];

    for (int i = t; i < n; i += 256) {
        unsigned p = edgebuf[base + i];
        int dl = (p >> 16) & 255;
        int pos = atomicAdd(&cur[dl], 1);
        if (pos < MAX_DEG) srow[dl * MAX_DEG + pos] = (unsigned short)(p & 0xFFFFu);
    }
    __syncthreads();
    // dense 32KB writeout as u32
    unsigned* sl32 = (unsigned*)slots;
    const unsigned* sr32 = (const unsigned*)srow;
    int gbase32 = b * 8192;                          // 256 rows * 32 u32
    for (int i = t; i < 8192; i += 256) {
        int node = b * 256 + (i >> 5);
        if (node < N_NODES) sl32[gbase32 + i] = sr32[i];
    }
    int node = b * 256 + t;
    if (node < N_NODES) deg[node] = cur[t];
}

// ---------------- segment-mean aggregation: one wave per node, u16 slot table ----------------
// Wave-uniform trip count so every ds_bpermute runs with full exec (R7 bug);
// accumulation predicated per-lane. Lanes >= deg sanitize their ID to 0.

__global__ __launch_bounds__(256) void agg1_k(const __bf16* __restrict__ feat,
                                              const int* __restrict__ deg_a,
                                              const unsigned short* __restrict__ slots,
                                              __bf16* __restrict__ agg) {
    int n = blockIdx.x * 4 + (threadIdx.x >> 6);
    if (n >= N_NODES) return;
    int lane = threadIdx.x & 63;
    int slot = lane >> 4, l = lane & 15;
    int deg = deg_a[n];
    int nit = (deg < MAX_DEG) ? deg : MAX_DEG;

    int ed = (lane < nit) ? (int)slots[n * MAX_DEG + lane] : 0;  // coalesced u16

    float s[8];
    #pragma unroll
    for (int e = 0; e < 8; ++e) s[e] = 0.f;

    int trips = (nit + 3) >> 2;       // wave-uniform
    int it = slot;
    int k = 0;
    for (; k + 1 < trips; k += 2, it += 8) {
        int sn0 = __builtin_amdgcn_ds_bpermute(it << 2, ed);        // full exec
        int sn1 = __builtin_amdgcn_ds_bpermute((it + 4) << 2, ed);  // full exec
        bf16x8 v0 = *(const bf16x8*)(feat + (size_t)sn0 * 128 + l * 8);
        bf16x8 v1 = *(const bf16x8*)(feat + (size_t)sn1 * 128 + l * 8);
        if (it < nit) {
            #pragma unroll
            for (int e = 0; e < 8; ++e) s[e] += (float)v0[e];
        }
        if (it + 4 < nit) {
            #pragma unroll
            for (int e = 0; e < 8; ++e) s[e] += (float)v1[e];
        }
    }
    if (k < trips) {
        int sn = __builtin_amdgcn_ds_bpermute(it << 2, ed);         // full exec
        bf16x8 v = *(const bf16x8*)(feat + (size_t)sn * 128 + l * 8);
        if (it < nit) {
            #pragma unroll
            for (int e = 0; e < 8; ++e) s[e] += (float)v[e];
        }
    }

    #pragma unroll
    for (int e = 0; e < 8; ++e) {
        s[e] += __shfl_xor(s[e], 16, 64);
        s[e] += __shfl_xor(s[e], 32, 64);
    }

    if (slot == 0) {
        float inv = 1.0f / fmaxf((float)deg, 1.0f);
        bf16x8 o;
        #pragma unroll
        for (int e = 0; e < 8; ++e) o[e] = (__bf16)(s[e] * inv);
        *(bf16x8*)(agg + (size_t)n * 128 + l * 8) = o;
    }
}

// ---------------- layer 1: out = relu([agg|feat] @ B + bias), 16 rows/wave ----------------

__global__ __launch_bounds__(256) void layer_mfma_k(const __bf16* __restrict__ agg,
                                                    const __bf16* __restrict__ feat,
                                                    const __bf16* __restrict__ wpack,
                                                    const float* __restrict__ bias,
                                                    __bf16* __restrict__ out) {
    int wave = threadIdx.x >> 6;
    int lane = threadIdx.x & 63;
    int m = lane & 15, quad = lane >> 4;
    int rbase = blockIdx.x * 64 + wave * 16;
    int r0 = rbase + m; if (r0 > N_NODES - 1) r0 = N_NODES - 1;

    f32x4 acc[8];
    #pragma unroll
    for (int nt = 0; nt < 8; ++nt) acc[nt] = (f32x4)0.f;

    #pragma unroll
    for (int kt = 0; kt < 8; ++kt) {
        const __bf16* src = (kt < 4) ? agg : feat;
        int ko = (kt & 3) * 32 + quad * 8;
        bf16x8 a0 = *(const bf16x8*)(src + (size_t)r0 * 128 + ko);
        const __bf16* wb = wpack + (size_t)kt * 4096 + lane * 8;
        #pragma unroll
        for (int nt = 0; nt < 8; ++nt) {
            bf16x8 b = *(const bf16x8*)(wb + nt * 512);
            acc[nt] = __builtin_amdgcn_mfma_f32_16x16x32_bf16(a0, b, acc[nt], 0, 0, 0);
        }
    }

    #pragma unroll
    for (int r = 0; r < 4; ++r) {
        int row = rbase + quad * 4 + r;
        if (row < N_NODES) {
            #pragma unroll
            for (int nt = 0; nt < 8; ++nt) {
                float v = acc[nt][r] + bias[nt * 16 + m];
                out[(size_t)row * 128 + nt * 16 + m] = (__bf16)fmaxf(v, 0.f);
            }
        }
    }
}

// ---------------- layer 2 + UV: h2 never hits global ----------------

__global__ __launch_bounds__(256) void layer2uv_k(const __bf16* __restrict__ agg,
                                                  const __bf16* __restrict__ feat,
                                                  const __bf16* __restrict__ wpack,
                                                  const float* __restrict__ bias,
                                                  const __bf16* __restrict__ wpack4,
                                                  _Float16* __restrict__ UV) {
    __shared__ __bf16 sh[4][16][136];   // 136: rows 16B-aligned (272 B)
    int wave = threadIdx.x >> 6;
    int lane = threadIdx.x & 63;
    int m = lane & 15, q = lane >> 4;
    int rbase = blockIdx.x * 64 + wave * 16;
    int r0 = rbase + m; if (r0 > N_NODES - 1) r0 = N_NODES - 1;

    f32x4 acc[8];
    #pragma unroll
    for (int nt = 0; nt < 8; ++nt) acc[nt] = (f32x4)0.f;

    #pragma unroll
    for (int kt = 0; kt < 8; ++kt) {
        const __bf16* src = (kt < 4) ? agg : feat;
        int ko = (kt & 3) * 32 + q * 8;
        bf16x8 a0 = *(const bf16x8*)(src + (size_t)r0 * 128 + ko);
        const __bf16* wb = wpack + (size_t)kt * 4096 + lane * 8;
        #pragma unroll
        for (int nt = 0; nt < 8; ++nt) {
            bf16x8 b = *(const bf16x8*)(wb + nt * 512);
            acc[nt] = __builtin_amdgcn_mfma_f32_16x16x32_bf16(a0, b, acc[nt], 0, 0, 0);
        }
    }

    // relu'd h2 tile -> wave-private LDS (C-layout scatter, within-wave only)
    #pragma unroll
    for (int rr = 0; rr < 4; ++rr)
        #pragma unroll
        for (int nt = 0; nt < 8; ++nt) {
            float v = acc[nt][rr] + bias[nt * 16 + m];
            sh[wave][q * 4 + rr][nt * 16 + m] = (__bf16)fmaxf(v, 0.f);
        }

    f32x4 acc2[16];
    #pragma unroll
    for (int nt = 0; nt < 16; ++nt) acc2[nt] = (f32x4)0.f;

    #pragma unroll
    for (int kt = 0; kt < 4; ++kt) {
        bf16x8 a = *(const bf16x8*)&sh[wave][m][kt * 32 + q * 8];
        const __bf16* wb = wpack4 + (size_t)kt * 8192 + lane * 8;
        #pragma unroll
        for (int nt = 0; nt < 16; ++nt) {
            bf16x8 b = *(const bf16x8*)(wb + nt * 512);
            acc2[nt] = __builtin_amdgcn_mfma_f32_16x16x32_bf16(a, b, acc2[nt], 0, 0, 0);
        }
    }

    #pragma unroll
    for (int rr = 0; rr < 4; ++rr) {
        int row = rbase + q * 4 + rr;
        if (row < N_NODES) {
            #pragma unroll
            for (int nt = 0; nt < 16; ++nt)
                UV[(size_t)row * 256 + nt * 16 + m] = (_Float16)acc2[nt][rr];
        }
    }
}

// ---------------- pair epilogue: sigmoid(relu(U[a]+V[b]+b3) . W4 + b4) ----------------

__global__ __launch_bounds__(256) void pair_ep_k(const _Float16* __restrict__ UV,
                                                 const int* __restrict__ pairs,
                                                 const float* __restrict__ b3,
                                                 const float* __restrict__ W4,
                                                 const float* __restrict__ b4,
                                                 float* __restrict__ out) {
    int t = threadIdx.x;
    int g = t >> 4, l = t & 15;
    int base = blockIdx.x * 64;

    float4 b3a = *(const float4*)(b3 + l * 8);
    float4 b3b = *(const float4*)(b3 + l * 8 + 4);
    float4 w4a = *(const float4*)(W4 + l * 8);
    float4 w4b = *(const float4*)(W4 + l * 8 + 4);
    float bb[8] = {b3a.x, b3a.y, b3a.z, b3a.w, b3b.x, b3b.y, b3b.z, b3b.w};
    float ww[8] = {w4a.x, w4a.y, w4a.z, w4a.w, w4b.x, w4b.y, w4b.z, w4b.w};
    float b4s = b4[0];

    int2 pr[4];
    #pragma unroll
    for (int i = 0; i < 4; ++i) pr[i] = ((const int2*)pairs)[base + i * 16 + g];

    f16x8 ua[4], vb[4];
    #pragma unroll
    for (int i = 0; i < 4; ++i) {
        ua[i] = *(const f16x8*)(UV + (size_t)pr[i].x * 256 + l * 8);
        vb[i] = *(const f16x8*)(UV + (size_t)pr[i].y * 256 + 128 + l * 8);
    }

    #pragma unroll
    for (int i = 0; i < 4; ++i) {
        float p = 0.f;
        #pragma unroll
        for (int e = 0; e < 8; ++e)
            p += fmaxf((float)ua[i][e] + (float)vb[i][e] + bb[e], 0.f) * ww[e];
        #pragma unroll
        for (int s = 1; s < 16; s <<= 1) p += __shfl_xor(p, s, 64);
        if (l == 0)
            out[base + i * 16 + g] = 1.0f / (1.0f + expf(-(p + b4s)));
    }
}

// ---------------- launch ----------------

extern "C" void kernel_launch(void* const* d_in, const int* in_sizes, int n_in,
                              void* d_out, int out_size, void* d_ws, size_t ws_size,
                              hipStream_t stream) {
    const float* x   = (const float*)d_in[0];
    const int*   ei  = (const int*)d_in[1];
    const int*   prs = (const int*)d_in[2];
    const float* Wl1 = (const float*)d_in[3];
    const float* Wr1 = (const float*)d_in[4];
    const float* b1  = (const float*)d_in[5];
    const float* Wl2 = (const float*)d_in[6];
    const float* Wr2 = (const float*)d_in[7];
    const float* b2  = (const float*)d_in[8];
    const float* W3  = (const float*)d_in[9];
    const float* b3  = (const float*)d_in[10];
    const float* W4  = (const float*)d_in[11];
    const float* b4  = (const float*)d_in[12];
    float* out = (float*)d_out;

    const int* srcv = ei;
    const int* dstv = ei + E_EDGES;

    char* ws = (char*)d_ws;
    size_t off = 0;
    auto alloc = [&](size_t bytes) -> void* {
        void* p = ws + off;
        off = (off + bytes + 255) & ~(size_t)255;
        return p;
    };
    int*            bucketCnt  = (int*)alloc(sizeof(int) * NB);
    int*            blockBase  = (int*)alloc(sizeof(int) * SORT_BLKS * NB);
    unsigned*       edgebuf    = (unsigned*)alloc(sizeof(unsigned) * E_EDGES);
    int*            deg        = (int*)alloc(sizeof(int) * N_NODES);
    unsigned short* slots      = (unsigned short*)alloc(sizeof(unsigned short) * (size_t)N_NODES * MAX_DEG + 512);
    __bf16*   P1     = (__bf16*)alloc(sizeof(__bf16) * 32768);
    __bf16*   P2     = (__bf16*)alloc(sizeof(__bf16) * 32768);
    __bf16*   P4     = (__bf16*)alloc(sizeof(__bf16) * 32768);
    __bf16*   xb     = (__bf16*)alloc(sizeof(__bf16) * (size_t)N_NODES * 128);
    __bf16*   aggb   = (__bf16*)alloc(sizeof(__bf16) * (size_t)N_NODES * 128);
    __bf16*   h1b    = (__bf16*)alloc(sizeof(__bf16) * (size_t)N_NODES * 128);
    _Float16* UV     = (_Float16*)alloc(sizeof(_Float16) * (size_t)N_NODES * 256);
    (void)ws_size; (void)in_sizes; (void)n_in; (void)out_size;

    hipMemsetAsync(bucketCnt, 0, sizeof(int) * NB, stream);

    // K1: bucket-count || conv_x || weight pack
    pre_k<<<SORT_BLKS + CONV_BLKS + PREP_BLKS, 256, 0, stream>>>(
        x, xb, dstv, bucketCnt, blockBase, Wl1, Wr1, Wl2, Wr2, W3, P1, P2, P4);
    // K2: place edges (bucket-sorted, coalesced; internal bucket scan)
    place_k<<<SORT_BLKS, 256, 0, stream>>>(srcv, dstv, bucketCnt, blockBase, edgebuf);
    // K3: build slot rows + deg (dense writes, LDS atomics only; internal scan)
    slots_k<<<NB, 256, 0, stream>>>(edgebuf, bucketCnt, slots, deg);

    // layer 1
    agg1_k<<<(N_NODES + 3) / 4, 256, 0, stream>>>(xb, deg, slots, aggb);
    layer_mfma_k<<<(N_NODES + 63) / 64, 256, 0, stream>>>(aggb, xb, P1, b1, h1b);
    // layer 2 + UV (h2 stays in registers/LDS)
    agg1_k<<<(N_NODES + 3) / 4, 256, 0, stream>>>(h1b, deg, slots, aggb);
    layer2uv_k<<<(N_NODES + 63) / 64, 256, 0, stream>>>(aggb, h1b, P2, b2, P4, UV);
    // pair scoring
    pair_ep_k<<<P_PAIRS / 64, 256, 0, stream>>>(UV, prs, b3, W4, b4, out);
}